// Round 1
// baseline (732.527 us; speedup 1.0000x reference)
//
#include <hip/hip_runtime.h>
#include <hip/hip_bf16.h>

// ---------------------------------------------------------------------------
// 2-layer GCN on MI355X.
// Pipeline per call (all on `stream`, graph-capture safe):
//   memset counts=0
//   k_count:    indeg[dst]++ over edges (int atomics)
//   k_scan:     exclusive prefix sum of counts -> offsets (single block)
//   k_dinv:     dinv[i]=rsqrt(indeg+1); cursor[i]=offsets[i]
//   k_fill:     CSR fill: csrc[slot]=src, cw[slot]=dinv[src]*dinv[dst]
//   k_gemm64:   h1 = emb @ W1            (F1 = ws feature buffer)
//   k_agg:      X1 = relu(agg(h1)+b1)    (written into d_out as scratch)
//   k_gemm64:   h2 = X1 @ W2             (F1, reuse)
//   k_agg:      out = relu(agg(h2)+b2)   (d_out final)
// ---------------------------------------------------------------------------

#define WAVE 64

__global__ __launch_bounds__(256) void k_count(const int* __restrict__ dst,
                                               int* __restrict__ counts, int ne) {
    int i = blockIdx.x * 256 + threadIdx.x;
    int stride = gridDim.x * 256;
    for (; i < ne; i += stride) {
        atomicAdd(&counts[dst[i]], 1);
    }
}

// single-block exclusive scan: 1024 threads = 16 waves, chunked
__global__ __launch_bounds__(1024) void k_scan(const int* __restrict__ counts,
                                               int* __restrict__ offsets, int n) {
    const int tid  = threadIdx.x;
    const int lane = tid & 63;
    const int wid  = tid >> 6;
    __shared__ int wsum[16];
    __shared__ int chunk_total;
    __shared__ int carry_s;
    if (tid == 0) carry_s = 0;
    __syncthreads();

    for (int base = 0; base < n; base += 1024) {
        int i = base + tid;
        int v = (i < n) ? counts[i] : 0;
        // inclusive wave scan
        int x = v;
        #pragma unroll
        for (int off = 1; off < 64; off <<= 1) {
            int t = __shfl_up(x, off);
            if (lane >= off) x += t;
        }
        if (lane == 63) wsum[wid] = x;
        __syncthreads();
        if (tid == 0) {
            int run = 0;
            #pragma unroll
            for (int w = 0; w < 16; ++w) { int t = wsum[w]; wsum[w] = run; run += t; }
            chunk_total = run;
        }
        __syncthreads();
        int excl = carry_s + wsum[wid] + (x - v);
        if (i < n) offsets[i] = excl;
        __syncthreads();
        if (tid == 0) carry_s += chunk_total;
        __syncthreads();
    }
    if (tid == 0) offsets[n] = carry_s;
}

__global__ __launch_bounds__(256) void k_dinv(const int* __restrict__ counts,
                                              const int* __restrict__ offsets,
                                              float* __restrict__ dinv,
                                              int* __restrict__ cursor, int n) {
    int i = blockIdx.x * 256 + threadIdx.x;
    if (i < n) {
        dinv[i]   = rsqrtf((float)(counts[i] + 1));  // +1 self loop; always > 0
        cursor[i] = offsets[i];
    }
}

__global__ __launch_bounds__(256) void k_fill(const int* __restrict__ src,
                                              const int* __restrict__ dst,
                                              const float* __restrict__ dinv,
                                              int* __restrict__ cursor,
                                              int* __restrict__ csrc,
                                              float* __restrict__ cw, int ne) {
    int i = blockIdx.x * 256 + threadIdx.x;
    int stride = gridDim.x * 256;
    for (; i < ne; i += stride) {
        int s = src[i], d = dst[i];
        int slot = atomicAdd(&cursor[d], 1);
        csrc[slot] = s;
        cw[slot]   = dinv[s] * dinv[d];
    }
}

// H[n,64] = X[n,64] @ W[64,64]; W staged in LDS; one wave per row.
__global__ __launch_bounds__(256) void k_gemm64(const float* __restrict__ X,
                                                const float* __restrict__ W,
                                                float* __restrict__ H, int n) {
    __shared__ float Wl[64 * 64];
    for (int t = threadIdx.x; t < 64 * 64; t += 256) Wl[t] = W[t];
    __syncthreads();
    const int lane = threadIdx.x & 63;
    int wid = (blockIdx.x * 256 + threadIdx.x) >> 6;
    const int nw = (gridDim.x * 256) >> 6;
    for (int r = wid; r < n; r += nw) {
        float xv  = X[r * 64 + lane];
        float acc = 0.f;
        #pragma unroll
        for (int k = 0; k < 64; ++k) {
            float xk = __shfl(xv, k);
            acc = fmaf(xk, Wl[k * 64 + lane], acc);
        }
        H[r * 64 + lane] = acc;
    }
}

// out[i,:] = relu( dinv[i]^2*H[i,:] + sum_e cw[e]*H[csrc[e],:] + bias )
// one wave per node; lane = feature dim
__global__ __launch_bounds__(256) void k_agg(const float* __restrict__ H,
                                             const float* __restrict__ bias,
                                             const int* __restrict__ offsets,
                                             const int* __restrict__ csrc,
                                             const float* __restrict__ cw,
                                             const float* __restrict__ dinv,
                                             float* __restrict__ out, int n) {
    const int lane = threadIdx.x & 63;
    int wid = (blockIdx.x * 256 + threadIdx.x) >> 6;
    const int nw = (gridDim.x * 256) >> 6;
    float b = bias[lane];
    for (int i = wid; i < n; i += nw) {
        float di  = dinv[i];
        float acc = di * di * H[i * 64 + lane];   // self loop
        int beg = offsets[i], end = offsets[i + 1];
        for (int base = beg; base < end; base += 64) {
            int e = base + lane;
            int s = 0; float w = 0.f;
            if (e < end) { s = csrc[e]; w = cw[e]; }
            int m = end - base; if (m > 64) m = 64;
            for (int j = 0; j < m; ++j) {
                int   ss = __shfl(s, j);
                float ww = __shfl(w, j);
                acc = fmaf(ww, H[ss * 64 + lane], acc);
            }
        }
        acc += b;
        out[i * 64 + lane] = fmaxf(acc, 0.f);
    }
}

extern "C" void kernel_launch(void* const* d_in, const int* in_sizes, int n_in,
                              void* d_out, int out_size, void* d_ws, size_t ws_size,
                              hipStream_t stream) {
    const float* emb = (const float*)d_in[0];
    const float* W1  = (const float*)d_in[1];
    const float* b1  = (const float*)d_in[2];
    const float* W2  = (const float*)d_in[3];
    const float* b2  = (const float*)d_in[4];
    const int*   ei  = (const int*)d_in[5];

    const int n  = in_sizes[0] / 64;   // 100000 nodes
    const int ne = in_sizes[5] / 2;    // 1600000 edges
    const int* src = ei;
    const int* dst = ei + ne;

    // ---- workspace layout ----
    char* ws = (char*)d_ws;
    size_t off = 0;
    auto alloc = [&](size_t bytes) { void* p = ws + off; off = (off + bytes + 63) & ~size_t(63); return p; };
    int*   counts  = (int*)  alloc((size_t)n * 4);
    int*   offsets = (int*)  alloc((size_t)(n + 1) * 4);
    int*   cursor  = (int*)  alloc((size_t)n * 4);
    float* dinv    = (float*)alloc((size_t)n * 4);
    int*   csrc    = (int*)  alloc((size_t)ne * 4);
    float* cw      = (float*)alloc((size_t)ne * 4);
    float* F1      = (float*)alloc((size_t)n * 64 * 4);   // feature scratch
    (void)ws_size;

    float* out = (float*)d_out;       // also used as X1 scratch between layers

    hipMemsetAsync(counts, 0, (size_t)n * 4, stream);

    const int eb = (ne + 255) / 256;        // edge-parallel blocks
    const int nb = (n + 255) / 256;         // node-parallel blocks
    const int wb = (n + 3) / 4;             // 1 wave per node, 4 waves/block

    k_count<<<eb, 256, 0, stream>>>(dst, counts, ne);
    k_scan<<<1, 1024, 0, stream>>>(counts, offsets, n);
    k_dinv<<<nb, 256, 0, stream>>>(counts, offsets, dinv, cursor, n);
    k_fill<<<eb, 256, 0, stream>>>(src, dst, dinv, cursor, csrc, cw, ne);

    // layer 1
    k_gemm64<<<wb, 256, 0, stream>>>(emb, W1, F1, n);
    k_agg<<<wb, 256, 0, stream>>>(F1, b1, offsets, csrc, cw, dinv, out, n);
    // layer 2
    k_gemm64<<<wb, 256, 0, stream>>>(out, W2, F1, n);
    k_agg<<<wb, 256, 0, stream>>>(F1, b2, offsets, csrc, cw, dinv, out, n);
}

// Round 2
// 458.067 us; speedup vs baseline: 1.5992x; 1.5992x over previous
//
#include <hip/hip_runtime.h>
#include <hip/hip_bf16.h>

// ---------------------------------------------------------------------------
// 2-layer GCN on MI355X, restructured:
//   relu(agg(X@W)+b) == relu(agg(X)@W + b)   (agg is linear)
// Pipeline:
//   memset counts; k_count; k_bsum/k_bscan/k_scan2 (offsets+dinv+cursor);
//   k_fill (CSR: csrc, cw)
//   k_agg(emb -> Y); k_gemm64(Y,W1,b1 -> d_out)   [bias+relu fused]
//   k_agg(d_out -> Y); k_gemm64(Y,W2,b2 -> d_out)
// ---------------------------------------------------------------------------

__global__ __launch_bounds__(256) void k_count(const int* __restrict__ dst,
                                               int* __restrict__ counts, int ne) {
    int i = blockIdx.x * 256 + threadIdx.x;
    if (i < ne) atomicAdd(&counts[dst[i]], 1);
}

// per-1024-chunk sums
__global__ __launch_bounds__(1024) void k_bsum(const int* __restrict__ counts,
                                               int* __restrict__ bsum, int n) {
    const int tid = threadIdx.x, lane = tid & 63, wid = tid >> 6;
    __shared__ int wsum[16];
    int i = blockIdx.x * 1024 + tid;
    int v = (i < n) ? counts[i] : 0;
    #pragma unroll
    for (int m = 1; m < 64; m <<= 1) v += __shfl_xor(v, m);
    if (lane == 0) wsum[wid] = v;
    __syncthreads();
    if (tid == 0) {
        int s = 0;
        #pragma unroll
        for (int w = 0; w < 16; ++w) s += wsum[w];
        bsum[blockIdx.x] = s;
    }
}

// exclusive scan of the B chunk sums (B ~ 98); single wave, chunked
__global__ __launch_bounds__(64) void k_bscan(const int* __restrict__ bsum,
                                              int* __restrict__ boff, int B,
                                              int* __restrict__ offsets, int n) {
    const int lane = threadIdx.x;
    int carry = 0;
    for (int base = 0; base < B; base += 64) {
        int i = base + lane;
        int v = (i < B) ? bsum[i] : 0;
        int x = v;
        #pragma unroll
        for (int off = 1; off < 64; off <<= 1) {
            int t = __shfl_up(x, off);
            if (lane >= off) x += t;
        }
        if (i < B) boff[i] = carry + x - v;
        carry += __shfl(x, 63);
    }
    if (lane == 0) offsets[n] = carry;
}

// per-chunk exclusive scan + carry; fuse dinv/cursor init
__global__ __launch_bounds__(1024) void k_scan2(const int* __restrict__ counts,
                                                const int* __restrict__ boff,
                                                int* __restrict__ offsets,
                                                float* __restrict__ dinv,
                                                int* __restrict__ cursor, int n) {
    const int tid = threadIdx.x, lane = tid & 63, wid = tid >> 6;
    __shared__ int wsum[16];
    int i = blockIdx.x * 1024 + tid;
    int v = (i < n) ? counts[i] : 0;
    int x = v;
    #pragma unroll
    for (int off = 1; off < 64; off <<= 1) {
        int t = __shfl_up(x, off);
        if (lane >= off) x += t;
    }
    if (lane == 63) wsum[wid] = x;
    __syncthreads();
    if (tid == 0) {
        int run = 0;
        #pragma unroll
        for (int w = 0; w < 16; ++w) { int t = wsum[w]; wsum[w] = run; run += t; }
    }
    __syncthreads();
    if (i < n) {
        int excl = boff[blockIdx.x] + wsum[wid] + (x - v);
        offsets[i] = excl;
        cursor[i]  = excl;
        dinv[i]    = rsqrtf((float)(v + 1));   // +1 self loop
    }
}

__global__ __launch_bounds__(256) void k_fill(const int* __restrict__ src,
                                              const int* __restrict__ dst,
                                              const float* __restrict__ dinv,
                                              int* __restrict__ cursor,
                                              int* __restrict__ csrc,
                                              float* __restrict__ cw, int ne) {
    int i = blockIdx.x * 256 + threadIdx.x;
    if (i < ne) {
        int s = src[i], d = dst[i];
        int slot = atomicAdd(&cursor[d], 1);
        csrc[slot] = s;
        cw[slot]   = dinv[s] * dinv[d];
    }
}

// Y[i,:] = dinv[i]^2 * X[i,:] + sum_e cw[e] * X[csrc[e],:]
// one wave per node; quarter-wave per edge, lane&15 -> feature group (x4)
__global__ __launch_bounds__(256) void k_agg(const float* __restrict__ X,
                                             const int* __restrict__ offsets,
                                             const int* __restrict__ csrc,
                                             const float* __restrict__ cw,
                                             const float* __restrict__ dinv,
                                             float* __restrict__ Y, int n) {
    const int lane = threadIdx.x & 63;
    const int sub  = lane >> 4;          // 0..3 edge sub-slot
    const int f0   = (lane & 15) * 4;    // feature offset
    const int i    = (blockIdx.x * 256 + threadIdx.x) >> 6;
    if (i >= n) return;
    const int beg = offsets[i], end = offsets[i + 1];
    float4 acc = {0.f, 0.f, 0.f, 0.f};
    for (int base = beg; base < end; base += 4) {
        const int e = base + sub;
        float w = 0.f; int s = 0;
        if (e < end) { s = csrc[e]; w = cw[e]; }
        const float4 h = *(const float4*)(X + (size_t)s * 64 + f0);
        acc.x = fmaf(w, h.x, acc.x);
        acc.y = fmaf(w, h.y, acc.y);
        acc.z = fmaf(w, h.z, acc.z);
        acc.w = fmaf(w, h.w, acc.w);
    }
    // reduce the 4 sub-slot partials (lanes l, l^16, l^32, l^48)
    acc.x += __shfl_xor(acc.x, 16); acc.x += __shfl_xor(acc.x, 32);
    acc.y += __shfl_xor(acc.y, 16); acc.y += __shfl_xor(acc.y, 32);
    acc.z += __shfl_xor(acc.z, 16); acc.z += __shfl_xor(acc.z, 32);
    acc.w += __shfl_xor(acc.w, 16); acc.w += __shfl_xor(acc.w, 32);
    const float di = dinv[i];
    const float w0 = di * di;
    const float4 xs = *(const float4*)(X + (size_t)i * 64 + f0);
    acc.x = fmaf(w0, xs.x, acc.x);
    acc.y = fmaf(w0, xs.y, acc.y);
    acc.z = fmaf(w0, xs.z, acc.z);
    acc.w = fmaf(w0, xs.w, acc.w);
    if (lane < 16) *(float4*)(Y + (size_t)i * 64 + f0) = acc;
}

// H = relu(X @ W + bias); 4x4 micro-tile per thread, 64x64 tile per block.
#define GEMM_ACC(ai, xi)                                                  \
    ai.x = fmaf(xi.x, w0.x, ai.x); ai.y = fmaf(xi.x, w0.y, ai.y);         \
    ai.z = fmaf(xi.x, w0.z, ai.z); ai.w = fmaf(xi.x, w0.w, ai.w);         \
    ai.x = fmaf(xi.y, w1.x, ai.x); ai.y = fmaf(xi.y, w1.y, ai.y);         \
    ai.z = fmaf(xi.y, w1.z, ai.z); ai.w = fmaf(xi.y, w1.w, ai.w);         \
    ai.x = fmaf(xi.z, w2.x, ai.x); ai.y = fmaf(xi.z, w2.y, ai.y);         \
    ai.z = fmaf(xi.z, w2.z, ai.z); ai.w = fmaf(xi.z, w2.w, ai.w);         \
    ai.x = fmaf(xi.w, w3.x, ai.x); ai.y = fmaf(xi.w, w3.y, ai.y);         \
    ai.z = fmaf(xi.w, w3.z, ai.z); ai.w = fmaf(xi.w, w3.w, ai.w);

#define GEMM_STORE(ai, idx)                                               \
    if (r0 + idx < n) {                                                   \
        float4 r;                                                         \
        r.x = fmaxf(ai.x + bv.x, 0.f); r.y = fmaxf(ai.y + bv.y, 0.f);     \
        r.z = fmaxf(ai.z + bv.z, 0.f); r.w = fmaxf(ai.w + bv.w, 0.f);     \
        *(float4*)(H + (size_t)(r0 + idx) * 64 + c0) = r;                 \
    }

__global__ __launch_bounds__(256) void k_gemm64(const float* __restrict__ X,
                                                const float* __restrict__ W,
                                                const float* __restrict__ bias,
                                                float* __restrict__ H, int n) {
    __shared__ float Wl[64 * 64];
    for (int t = threadIdx.x; t < 64 * 64; t += 256) Wl[t] = W[t];
    __syncthreads();
    const int cg = threadIdx.x & 15;     // col group
    const int rg = threadIdx.x >> 4;     // row group
    const int c0 = cg * 4;
    const float4 bv = *(const float4*)(bias + c0);
    const int ntile = (n + 63) >> 6;
    for (int t = blockIdx.x; t < ntile; t += gridDim.x) {
        const int r0 = t * 64 + rg * 4;
        const float* xp0 = X + (size_t)min(r0 + 0, n - 1) * 64;
        const float* xp1 = X + (size_t)min(r0 + 1, n - 1) * 64;
        const float* xp2 = X + (size_t)min(r0 + 2, n - 1) * 64;
        const float* xp3 = X + (size_t)min(r0 + 3, n - 1) * 64;
        float4 a0 = {0,0,0,0}, a1 = {0,0,0,0}, a2 = {0,0,0,0}, a3 = {0,0,0,0};
        #pragma unroll
        for (int k = 0; k < 64; k += 4) {
            const float4 x0 = *(const float4*)(xp0 + k);
            const float4 x1 = *(const float4*)(xp1 + k);
            const float4 x2 = *(const float4*)(xp2 + k);
            const float4 x3 = *(const float4*)(xp3 + k);
            const float4 w0 = *(const float4*)(&Wl[(k + 0) * 64 + c0]);
            const float4 w1 = *(const float4*)(&Wl[(k + 1) * 64 + c0]);
            const float4 w2 = *(const float4*)(&Wl[(k + 2) * 64 + c0]);
            const float4 w3 = *(const float4*)(&Wl[(k + 3) * 64 + c0]);
            GEMM_ACC(a0, x0)
            GEMM_ACC(a1, x1)
            GEMM_ACC(a2, x2)
            GEMM_ACC(a3, x3)
        }
        GEMM_STORE(a0, 0)
        GEMM_STORE(a1, 1)
        GEMM_STORE(a2, 2)
        GEMM_STORE(a3, 3)
    }
}

extern "C" void kernel_launch(void* const* d_in, const int* in_sizes, int n_in,
                              void* d_out, int out_size, void* d_ws, size_t ws_size,
                              hipStream_t stream) {
    const float* emb = (const float*)d_in[0];
    const float* W1  = (const float*)d_in[1];
    const float* b1  = (const float*)d_in[2];
    const float* W2  = (const float*)d_in[3];
    const float* b2  = (const float*)d_in[4];
    const int*   ei  = (const int*)d_in[5];

    const int n  = in_sizes[0] / 64;   // 100000 nodes
    const int ne = in_sizes[5] / 2;    // 1600000 edges
    const int* src = ei;
    const int* dst = ei + ne;
    const int B = (n + 1023) / 1024;   // scan chunks

    // ---- workspace layout (~40 MB) ----
    char* ws = (char*)d_ws;
    size_t off = 0;
    auto alloc = [&](size_t bytes) { void* p = ws + off; off = (off + bytes + 63) & ~size_t(63); return p; };
    int*   counts  = (int*)  alloc((size_t)n * 4);
    int*   offsets = (int*)  alloc((size_t)(n + 1) * 4);
    int*   cursor  = (int*)  alloc((size_t)n * 4);
    float* dinv    = (float*)alloc((size_t)n * 4);
    int*   bsum    = (int*)  alloc((size_t)B * 4);
    int*   boff    = (int*)  alloc((size_t)B * 4);
    int*   csrc    = (int*)  alloc((size_t)ne * 4);
    float* cw      = (float*)alloc((size_t)ne * 4);
    float* Y       = (float*)alloc((size_t)n * 64 * 4);
    (void)ws_size;

    float* out = (float*)d_out;   // doubles as X1 between the layers

    hipMemsetAsync(counts, 0, (size_t)n * 4, stream);

    const int eb = (ne + 255) / 256;
    const int wb = (n + 3) / 4;          // 1 wave per node
    const int gb = min((n + 63) / 64, 2048);

    k_count<<<eb, 256, 0, stream>>>(dst, counts, ne);
    k_bsum <<<B, 1024, 0, stream>>>(counts, bsum, n);
    k_bscan<<<1, 64, 0, stream>>>(bsum, boff, B, offsets, n);
    k_scan2<<<B, 1024, 0, stream>>>(counts, boff, offsets, dinv, cursor, n);
    k_fill <<<eb, 256, 0, stream>>>(src, dst, dinv, cursor, csrc, cw, ne);

    // layer 1
    k_agg   <<<wb, 256, 0, stream>>>(emb, offsets, csrc, cw, dinv, Y, n);
    k_gemm64<<<gb, 256, 0, stream>>>(Y, W1, b1, out, n);
    // layer 2
    k_agg   <<<wb, 256, 0, stream>>>(out, offsets, csrc, cw, dinv, Y, n);
    k_gemm64<<<gb, 256, 0, stream>>>(Y, W2, b2, out, n);
}

// Round 3
// 414.456 us; speedup vs baseline: 1.7674x; 1.1052x over previous
//
#include <hip/hip_runtime.h>
#include <hip/hip_bf16.h>

// ---------------------------------------------------------------------------
// 2-layer GCN on MI355X.
//   relu(agg(X@W)+b) == relu(agg(X)@W + b)   (agg is linear)
// Pipeline:
//   memset counts; k_count; k_bsum/k_bscan/k_scan2 (offsets+dinv+cursor);
//   k_fill (CSR: cpack = {src, w} packed 8B, ONE scatter per edge)
//   k_agg(emb -> Y); k_gemm64(Y,W1,b1 -> d_out)   [bias+relu fused]
//   k_agg(d_out -> Y); k_gemm64(Y,W2,b2 -> d_out)
// ---------------------------------------------------------------------------

__global__ __launch_bounds__(256) void k_count(const int* __restrict__ dst,
                                               int* __restrict__ counts, int ne) {
    int i = (blockIdx.x * 256 + threadIdx.x) * 2;
    if (i + 1 < ne) {
        int2 d = *(const int2*)(dst + i);
        atomicAdd(&counts[d.x], 1);
        atomicAdd(&counts[d.y], 1);
    } else if (i < ne) {
        atomicAdd(&counts[dst[i]], 1);
    }
}

// per-1024-chunk sums
__global__ __launch_bounds__(1024) void k_bsum(const int* __restrict__ counts,
                                               int* __restrict__ bsum, int n) {
    const int tid = threadIdx.x, lane = tid & 63, wid = tid >> 6;
    __shared__ int wsum[16];
    int i = blockIdx.x * 1024 + tid;
    int v = (i < n) ? counts[i] : 0;
    #pragma unroll
    for (int m = 1; m < 64; m <<= 1) v += __shfl_xor(v, m);
    if (lane == 0) wsum[wid] = v;
    __syncthreads();
    if (tid == 0) {
        int s = 0;
        #pragma unroll
        for (int w = 0; w < 16; ++w) s += wsum[w];
        bsum[blockIdx.x] = s;
    }
}

// exclusive scan of the B chunk sums (B ~ 98); single wave, chunked
__global__ __launch_bounds__(64) void k_bscan(const int* __restrict__ bsum,
                                              int* __restrict__ boff, int B,
                                              int* __restrict__ offsets, int n) {
    const int lane = threadIdx.x;
    int carry = 0;
    for (int base = 0; base < B; base += 64) {
        int i = base + lane;
        int v = (i < B) ? bsum[i] : 0;
        int x = v;
        #pragma unroll
        for (int off = 1; off < 64; off <<= 1) {
            int t = __shfl_up(x, off);
            if (lane >= off) x += t;
        }
        if (i < B) boff[i] = carry + x - v;
        carry += __shfl(x, 63);
    }
    if (lane == 0) offsets[n] = carry;
}

// per-chunk exclusive scan + carry; fuse dinv/cursor init
__global__ __launch_bounds__(1024) void k_scan2(const int* __restrict__ counts,
                                                const int* __restrict__ boff,
                                                int* __restrict__ offsets,
                                                float* __restrict__ dinv,
                                                int* __restrict__ cursor, int n) {
    const int tid = threadIdx.x, lane = tid & 63, wid = tid >> 6;
    __shared__ int wsum[16];
    int i = blockIdx.x * 1024 + tid;
    int v = (i < n) ? counts[i] : 0;
    int x = v;
    #pragma unroll
    for (int off = 1; off < 64; off <<= 1) {
        int t = __shfl_up(x, off);
        if (lane >= off) x += t;
    }
    if (lane == 63) wsum[wid] = x;
    __syncthreads();
    if (tid == 0) {
        int run = 0;
        #pragma unroll
        for (int w = 0; w < 16; ++w) { int t = wsum[w]; wsum[w] = run; run += t; }
    }
    __syncthreads();
    if (i < n) {
        int excl = boff[blockIdx.x] + wsum[wid] + (x - v);
        offsets[i] = excl;
        cursor[i]  = excl;
        dinv[i]    = rsqrtf((float)(v + 1));   // +1 self loop
    }
}

// ONE 8B scatter per edge: cpack[slot] = {src, bits(dinv[s]*dinv[d])}
__global__ __launch_bounds__(256) void k_fill(const int* __restrict__ src,
                                              const int* __restrict__ dst,
                                              const float* __restrict__ dinv,
                                              int* __restrict__ cursor,
                                              uint2* __restrict__ cpack, int ne) {
    int i = (blockIdx.x * 256 + threadIdx.x) * 2;
    if (i + 1 < ne) {
        int2 s2 = *(const int2*)(src + i);
        int2 d2 = *(const int2*)(dst + i);
        {
            int slot = atomicAdd(&cursor[d2.x], 1);
            uint2 p; p.x = (unsigned)s2.x;
            p.y = __float_as_uint(dinv[s2.x] * dinv[d2.x]);
            cpack[slot] = p;
        }
        {
            int slot = atomicAdd(&cursor[d2.y], 1);
            uint2 p; p.x = (unsigned)s2.y;
            p.y = __float_as_uint(dinv[s2.y] * dinv[d2.y]);
            cpack[slot] = p;
        }
    } else if (i < ne) {
        int s = src[i], d = dst[i];
        int slot = atomicAdd(&cursor[d], 1);
        uint2 p; p.x = (unsigned)s;
        p.y = __float_as_uint(dinv[s] * dinv[d]);
        cpack[slot] = p;
    }
}

// Y[i,:] = dinv[i]^2 * X[i,:] + sum_e w[e] * X[s[e],:]
// one wave per node; quarter-wave per edge, lane&15 -> feature group (x4)
__global__ __launch_bounds__(256) void k_agg(const float* __restrict__ X,
                                             const int* __restrict__ offsets,
                                             const uint2* __restrict__ cpack,
                                             const float* __restrict__ dinv,
                                             float* __restrict__ Y, int n) {
    const int lane = threadIdx.x & 63;
    const int sub  = lane >> 4;          // 0..3 edge sub-slot
    const int f0   = (lane & 15) * 4;    // feature offset
    const int i    = (blockIdx.x * 256 + threadIdx.x) >> 6;
    if (i >= n) return;
    const int beg = offsets[i], end = offsets[i + 1];
    float4 acc = {0.f, 0.f, 0.f, 0.f};
    for (int base = beg; base < end; base += 4) {
        const int e = base + sub;
        float w = 0.f; unsigned s = 0;
        if (e < end) {
            uint2 p = cpack[e];
            s = p.x; w = __uint_as_float(p.y);
        }
        const float4 h = *(const float4*)(X + (size_t)s * 64 + f0);
        acc.x = fmaf(w, h.x, acc.x);
        acc.y = fmaf(w, h.y, acc.y);
        acc.z = fmaf(w, h.z, acc.z);
        acc.w = fmaf(w, h.w, acc.w);
    }
    // reduce the 4 sub-slot partials (lanes l, l^16, l^32, l^48)
    acc.x += __shfl_xor(acc.x, 16); acc.x += __shfl_xor(acc.x, 32);
    acc.y += __shfl_xor(acc.y, 16); acc.y += __shfl_xor(acc.y, 32);
    acc.z += __shfl_xor(acc.z, 16); acc.z += __shfl_xor(acc.z, 32);
    acc.w += __shfl_xor(acc.w, 16); acc.w += __shfl_xor(acc.w, 32);
    const float di = dinv[i];
    const float w0 = di * di;
    const float4 xs = *(const float4*)(X + (size_t)i * 64 + f0);
    acc.x = fmaf(w0, xs.x, acc.x);
    acc.y = fmaf(w0, xs.y, acc.y);
    acc.z = fmaf(w0, xs.z, acc.z);
    acc.w = fmaf(w0, xs.w, acc.w);
    if (lane < 16) *(float4*)(Y + (size_t)i * 64 + f0) = acc;
}

// H = relu(X @ W + bias); 4x4 micro-tile per thread, 64x64 tile per block.
#define GEMM_ACC(ai, xi)                                                  \
    ai.x = fmaf(xi.x, w0.x, ai.x); ai.y = fmaf(xi.x, w0.y, ai.y);         \
    ai.z = fmaf(xi.x, w0.z, ai.z); ai.w = fmaf(xi.x, w0.w, ai.w);         \
    ai.x = fmaf(xi.y, w1.x, ai.x); ai.y = fmaf(xi.y, w1.y, ai.y);         \
    ai.z = fmaf(xi.y, w1.z, ai.z); ai.w = fmaf(xi.y, w1.w, ai.w);         \
    ai.x = fmaf(xi.z, w2.x, ai.x); ai.y = fmaf(xi.z, w2.y, ai.y);         \
    ai.z = fmaf(xi.z, w2.z, ai.z); ai.w = fmaf(xi.z, w2.w, ai.w);         \
    ai.x = fmaf(xi.w, w3.x, ai.x); ai.y = fmaf(xi.w, w3.y, ai.y);         \
    ai.z = fmaf(xi.w, w3.z, ai.z); ai.w = fmaf(xi.w, w3.w, ai.w);

#define GEMM_STORE(ai, idx)                                               \
    if (r0 + idx < n) {                                                   \
        float4 r;                                                         \
        r.x = fmaxf(ai.x + bv.x, 0.f); r.y = fmaxf(ai.y + bv.y, 0.f);     \
        r.z = fmaxf(ai.z + bv.z, 0.f); r.w = fmaxf(ai.w + bv.w, 0.f);     \
        *(float4*)(H + (size_t)(r0 + idx) * 64 + c0) = r;                 \
    }

__global__ __launch_bounds__(256) void k_gemm64(const float* __restrict__ X,
                                                const float* __restrict__ W,
                                                const float* __restrict__ bias,
                                                float* __restrict__ H, int n) {
    __shared__ float Wl[64 * 64];
    for (int t = threadIdx.x; t < 64 * 64; t += 256) Wl[t] = W[t];
    __syncthreads();
    const int cg = threadIdx.x & 15;     // col group
    const int rg = threadIdx.x >> 4;     // row group
    const int c0 = cg * 4;
    const float4 bv = *(const float4*)(bias + c0);
    const int ntile = (n + 63) >> 6;
    for (int t = blockIdx.x; t < ntile; t += gridDim.x) {
        const int r0 = t * 64 + rg * 4;
        const float* xp0 = X + (size_t)min(r0 + 0, n - 1) * 64;
        const float* xp1 = X + (size_t)min(r0 + 1, n - 1) * 64;
        const float* xp2 = X + (size_t)min(r0 + 2, n - 1) * 64;
        const float* xp3 = X + (size_t)min(r0 + 3, n - 1) * 64;
        float4 a0 = {0,0,0,0}, a1 = {0,0,0,0}, a2 = {0,0,0,0}, a3 = {0,0,0,0};
        #pragma unroll
        for (int k = 0; k < 64; k += 4) {
            const float4 x0 = *(const float4*)(xp0 + k);
            const float4 x1 = *(const float4*)(xp1 + k);
            const float4 x2 = *(const float4*)(xp2 + k);
            const float4 x3 = *(const float4*)(xp3 + k);
            const float4 w0 = *(const float4*)(&Wl[(k + 0) * 64 + c0]);
            const float4 w1 = *(const float4*)(&Wl[(k + 1) * 64 + c0]);
            const float4 w2 = *(const float4*)(&Wl[(k + 2) * 64 + c0]);
            const float4 w3 = *(const float4*)(&Wl[(k + 3) * 64 + c0]);
            GEMM_ACC(a0, x0)
            GEMM_ACC(a1, x1)
            GEMM_ACC(a2, x2)
            GEMM_ACC(a3, x3)
        }
        GEMM_STORE(a0, 0)
        GEMM_STORE(a1, 1)
        GEMM_STORE(a2, 2)
        GEMM_STORE(a3, 3)
    }
}

extern "C" void kernel_launch(void* const* d_in, const int* in_sizes, int n_in,
                              void* d_out, int out_size, void* d_ws, size_t ws_size,
                              hipStream_t stream) {
    const float* emb = (const float*)d_in[0];
    const float* W1  = (const float*)d_in[1];
    const float* b1  = (const float*)d_in[2];
    const float* W2  = (const float*)d_in[3];
    const float* b2  = (const float*)d_in[4];
    const int*   ei  = (const int*)d_in[5];

    const int n  = in_sizes[0] / 64;   // 100000 nodes
    const int ne = in_sizes[5] / 2;    // 1600000 edges
    const int* src = ei;
    const int* dst = ei + ne;
    const int B = (n + 1023) / 1024;   // scan chunks

    // ---- workspace layout (~40 MB) ----
    char* ws = (char*)d_ws;
    size_t off = 0;
    auto alloc = [&](size_t bytes) { void* p = ws + off; off = (off + bytes + 63) & ~size_t(63); return p; };
    int*   counts  = (int*)  alloc((size_t)n * 4);
    int*   offsets = (int*)  alloc((size_t)(n + 1) * 4);
    int*   cursor  = (int*)  alloc((size_t)n * 4);
    float* dinv    = (float*)alloc((size_t)n * 4);
    int*   bsum    = (int*)  alloc((size_t)B * 4);
    int*   boff    = (int*)  alloc((size_t)B * 4);
    uint2* cpack   = (uint2*)alloc((size_t)ne * 8);
    float* Y       = (float*)alloc((size_t)n * 64 * 4);
    (void)ws_size;

    float* out = (float*)d_out;   // doubles as X1 between the layers

    hipMemsetAsync(counts, 0, (size_t)n * 4, stream);

    const int e2b = (ne / 2 + 255) / 256;   // 2 edges per thread
    const int wb  = (n + 3) / 4;            // 1 wave per node
    const int gb  = min((n + 63) / 64, 2048);

    k_count<<<e2b, 256, 0, stream>>>(dst, counts, ne);
    k_bsum <<<B, 1024, 0, stream>>>(counts, bsum, n);
    k_bscan<<<1, 64, 0, stream>>>(bsum, boff, B, offsets, n);
    k_scan2<<<B, 1024, 0, stream>>>(counts, boff, offsets, dinv, cursor, n);
    k_fill <<<e2b, 256, 0, stream>>>(src, dst, dinv, cursor, cpack, ne);

    // layer 1
    k_agg   <<<wb, 256, 0, stream>>>(emb, offsets, cpack, dinv, Y, n);
    k_gemm64<<<gb, 256, 0, stream>>>(Y, W1, b1, out, n);
    // layer 2
    k_agg   <<<wb, 256, 0, stream>>>(out, offsets, cpack, dinv, Y, n);
    k_gemm64<<<gb, 256, 0, stream>>>(Y, W2, b2, out, n);
}

// Round 4
// 354.484 us; speedup vs baseline: 2.0665x; 1.1692x over previous
//
#include <hip/hip_runtime.h>
#include <hip/hip_bf16.h>

// ---------------------------------------------------------------------------
// 2-layer GCN on MI355X.
//   relu(agg(X@W)+b) == relu(agg(X)@W + b)   (agg is linear)
// CSR build WITHOUT random scatter (write-amplification fix):
//   k_bhist: bucket (dst>>7) histogram, LDS-staged
//   k_bscan: scan bucket counts -> bbase/bcur; offsets[n]=ne
//   k_part:  partition edges into buckets; per-block contiguous reservation
//            -> writes are block-exclusive & clustered (tpack, 4B/edge)
//   k_bin:   block per bucket: per-dst hist -> offsets+dinv (no global
//            atomics), LDS scan, write csrc grouped by dst (block-exclusive)
//   k_agg:   wave per node, gather X[src] rows, w = dinv[s]*dinv[d]
//   k_gemm64: fused bias+relu 64x64 GEMM
// Requires n < 2^17 (src packed in 17 bits; n = 100000 here).
// ---------------------------------------------------------------------------

#define NB_SHIFT 7
#define NB_MASK  ((1 << NB_SHIFT) - 1)
#define EPB      8192              // edges per block in bhist/part

__global__ __launch_bounds__(256) void k_bhist(const int* __restrict__ dst,
                                               int* __restrict__ bcnt,
                                               int ne, int nb) {
    __shared__ int lh[1024];
    for (int t = threadIdx.x; t < nb; t += 256) lh[t] = 0;
    __syncthreads();
    const int beg = blockIdx.x * EPB;
    const int end = min(beg + EPB, ne);
    for (int e = beg + threadIdx.x; e < end; e += 256)
        atomicAdd(&lh[dst[e] >> NB_SHIFT], 1);
    __syncthreads();
    for (int t = threadIdx.x; t < nb; t += 256)
        if (lh[t]) atomicAdd(&bcnt[t], lh[t]);
}

__global__ __launch_bounds__(64) void k_bscan(const int* __restrict__ bcnt,
                                              int* __restrict__ bbase,
                                              int* __restrict__ bcur, int nb,
                                              int* __restrict__ offsets,
                                              int n, int ne) {
    const int lane = threadIdx.x;
    int carry = 0;
    for (int base = 0; base < nb; base += 64) {
        int i = base + lane;
        int v = (i < nb) ? bcnt[i] : 0;
        int x = v;
        #pragma unroll
        for (int off = 1; off < 64; off <<= 1) {
            int t = __shfl_up(x, off);
            if (lane >= off) x += t;
        }
        if (i < nb) { int excl = carry + x - v; bbase[i] = excl; bcur[i] = excl; }
        carry += __shfl(x, 63);
    }
    if (lane == 0) { bbase[nb] = carry; offsets[n] = ne; }
}

__global__ __launch_bounds__(256) void k_part(const int* __restrict__ src,
                                              const int* __restrict__ dst,
                                              int* __restrict__ bcur,
                                              unsigned* __restrict__ tpack,
                                              int ne, int nb) {
    __shared__ int lh[1024];
    __shared__ int lbase[1024];
    __shared__ int lrk[1024];
    for (int t = threadIdx.x; t < nb; t += 256) { lh[t] = 0; lrk[t] = 0; }
    __syncthreads();
    const int beg = blockIdx.x * EPB;
    const int end = min(beg + EPB, ne);
    for (int e = beg + threadIdx.x; e < end; e += 256)
        atomicAdd(&lh[dst[e] >> NB_SHIFT], 1);
    __syncthreads();
    for (int t = threadIdx.x; t < nb; t += 256)
        lbase[t] = lh[t] ? atomicAdd(&bcur[t], lh[t]) : 0;
    __syncthreads();
    for (int e = beg + threadIdx.x; e < end; e += 256) {
        int d = dst[e], s = src[e];
        int b = d >> NB_SHIFT;
        int r = atomicAdd(&lrk[b], 1);
        tpack[lbase[b] + r] = (unsigned)s | ((unsigned)(d & NB_MASK) << 17);
    }
}

__global__ __launch_bounds__(256) void k_bin(const unsigned* __restrict__ tpack,
                                             const int* __restrict__ bbase,
                                             int* __restrict__ csrc,
                                             int* __restrict__ offsets,
                                             float* __restrict__ dinv, int n) {
    __shared__ int hist[128], loff[128], cur[128];
    const int b = blockIdx.x;
    const int ebeg = bbase[b], eend = bbase[b + 1];
    const int dbase = b << NB_SHIFT;
    if (threadIdx.x < 128) { hist[threadIdx.x] = 0; cur[threadIdx.x] = 0; }
    __syncthreads();
    for (int e = ebeg + threadIdx.x; e < eend; e += 256)
        atomicAdd(&hist[tpack[e] >> 17], 1);
    __syncthreads();
    if (threadIdx.x < 64) {   // wave 0: exclusive scan of hist[0..127]
        const int lane = threadIdx.x;
        int v0 = hist[lane], v1 = hist[64 + lane];
        int x0 = v0, x1 = v1;
        #pragma unroll
        for (int off = 1; off < 64; off <<= 1) {
            int t0 = __shfl_up(x0, off); if (lane >= off) x0 += t0;
            int t1 = __shfl_up(x1, off); if (lane >= off) x1 += t1;
        }
        int sum0 = __shfl(x0, 63);
        loff[lane]      = x0 - v0;
        loff[64 + lane] = sum0 + x1 - v1;
    }
    __syncthreads();
    if (threadIdx.x < 128) {
        int d = dbase + threadIdx.x;
        if (d < n) {
            offsets[d] = ebeg + loff[threadIdx.x];
            dinv[d]    = rsqrtf((float)(hist[threadIdx.x] + 1));  // +1 self loop
        }
    }
    __syncthreads();
    for (int e = ebeg + threadIdx.x; e < eend; e += 256) {
        unsigned p = tpack[e];
        int dl = (int)(p >> 17);
        int s  = (int)(p & 0x1FFFFu);
        int r  = atomicAdd(&cur[dl], 1);
        csrc[ebeg + loff[dl] + r] = s;
    }
}

// Y[i,:] = dinv[i]^2 * X[i,:] + sum_e dinv[s]*dinv[i] * X[s,:]
// one wave per node; quarter-wave per edge, lane&15 -> feature group (x4)
__global__ __launch_bounds__(256) void k_agg(const float* __restrict__ X,
                                             const int* __restrict__ offsets,
                                             const int* __restrict__ csrc,
                                             const float* __restrict__ dinv,
                                             float* __restrict__ Y, int n) {
    const int lane = threadIdx.x & 63;
    const int sub  = lane >> 4;          // 0..3 edge sub-slot
    const int f0   = (lane & 15) * 4;    // feature offset
    const int i    = (blockIdx.x * 256 + threadIdx.x) >> 6;
    if (i >= n) return;
    const int beg = offsets[i], end = offsets[i + 1];
    const float di = dinv[i];
    float4 acc = {0.f, 0.f, 0.f, 0.f};
    for (int base = beg; base < end; base += 4) {
        const int e = base + sub;
        float w = 0.f; int s = 0;
        if (e < end) { s = csrc[e]; w = dinv[s] * di; }
        const float4 h = *(const float4*)(X + (size_t)s * 64 + f0);
        acc.x = fmaf(w, h.x, acc.x);
        acc.y = fmaf(w, h.y, acc.y);
        acc.z = fmaf(w, h.z, acc.z);
        acc.w = fmaf(w, h.w, acc.w);
    }
    acc.x += __shfl_xor(acc.x, 16); acc.x += __shfl_xor(acc.x, 32);
    acc.y += __shfl_xor(acc.y, 16); acc.y += __shfl_xor(acc.y, 32);
    acc.z += __shfl_xor(acc.z, 16); acc.z += __shfl_xor(acc.z, 32);
    acc.w += __shfl_xor(acc.w, 16); acc.w += __shfl_xor(acc.w, 32);
    const float w0 = di * di;
    const float4 xs = *(const float4*)(X + (size_t)i * 64 + f0);
    acc.x = fmaf(w0, xs.x, acc.x);
    acc.y = fmaf(w0, xs.y, acc.y);
    acc.z = fmaf(w0, xs.z, acc.z);
    acc.w = fmaf(w0, xs.w, acc.w);
    if (lane < 16) *(float4*)(Y + (size_t)i * 64 + f0) = acc;
}

// H = relu(X @ W + bias); 4x4 micro-tile per thread, 64x64 tile per block.
#define GEMM_ACC(ai, xi)                                                  \
    ai.x = fmaf(xi.x, w0.x, ai.x); ai.y = fmaf(xi.x, w0.y, ai.y);         \
    ai.z = fmaf(xi.x, w0.z, ai.z); ai.w = fmaf(xi.x, w0.w, ai.w);         \
    ai.x = fmaf(xi.y, w1.x, ai.x); ai.y = fmaf(xi.y, w1.y, ai.y);         \
    ai.z = fmaf(xi.y, w1.z, ai.z); ai.w = fmaf(xi.y, w1.w, ai.w);         \
    ai.x = fmaf(xi.z, w2.x, ai.x); ai.y = fmaf(xi.z, w2.y, ai.y);         \
    ai.z = fmaf(xi.z, w2.z, ai.z); ai.w = fmaf(xi.z, w2.w, ai.w);         \
    ai.x = fmaf(xi.w, w3.x, ai.x); ai.y = fmaf(xi.w, w3.y, ai.y);         \
    ai.z = fmaf(xi.w, w3.z, ai.z); ai.w = fmaf(xi.w, w3.w, ai.w);

#define GEMM_STORE(ai, idx)                                               \
    if (r0 + idx < n) {                                                   \
        float4 r;                                                         \
        r.x = fmaxf(ai.x + bv.x, 0.f); r.y = fmaxf(ai.y + bv.y, 0.f);     \
        r.z = fmaxf(ai.z + bv.z, 0.f); r.w = fmaxf(ai.w + bv.w, 0.f);     \
        *(float4*)(H + (size_t)(r0 + idx) * 64 + c0) = r;                 \
    }

__global__ __launch_bounds__(256) void k_gemm64(const float* __restrict__ X,
                                                const float* __restrict__ W,
                                                const float* __restrict__ bias,
                                                float* __restrict__ H, int n) {
    __shared__ float Wl[64 * 64];
    for (int t = threadIdx.x; t < 64 * 64; t += 256) Wl[t] = W[t];
    __syncthreads();
    const int cg = threadIdx.x & 15;     // col group
    const int rg = threadIdx.x >> 4;     // row group
    const int c0 = cg * 4;
    const float4 bv = *(const float4*)(bias + c0);
    const int ntile = (n + 63) >> 6;
    for (int t = blockIdx.x; t < ntile; t += gridDim.x) {
        const int r0 = t * 64 + rg * 4;
        const float* xp0 = X + (size_t)min(r0 + 0, n - 1) * 64;
        const float* xp1 = X + (size_t)min(r0 + 1, n - 1) * 64;
        const float* xp2 = X + (size_t)min(r0 + 2, n - 1) * 64;
        const float* xp3 = X + (size_t)min(r0 + 3, n - 1) * 64;
        float4 a0 = {0,0,0,0}, a1 = {0,0,0,0}, a2 = {0,0,0,0}, a3 = {0,0,0,0};
        #pragma unroll
        for (int k = 0; k < 64; k += 4) {
            const float4 x0 = *(const float4*)(xp0 + k);
            const float4 x1 = *(const float4*)(xp1 + k);
            const float4 x2 = *(const float4*)(xp2 + k);
            const float4 x3 = *(const float4*)(xp3 + k);
            const float4 w0 = *(const float4*)(&Wl[(k + 0) * 64 + c0]);
            const float4 w1 = *(const float4*)(&Wl[(k + 1) * 64 + c0]);
            const float4 w2 = *(const float4*)(&Wl[(k + 2) * 64 + c0]);
            const float4 w3 = *(const float4*)(&Wl[(k + 3) * 64 + c0]);
            GEMM_ACC(a0, x0)
            GEMM_ACC(a1, x1)
            GEMM_ACC(a2, x2)
            GEMM_ACC(a3, x3)
        }
        GEMM_STORE(a0, 0)
        GEMM_STORE(a1, 1)
        GEMM_STORE(a2, 2)
        GEMM_STORE(a3, 3)
    }
}

extern "C" void kernel_launch(void* const* d_in, const int* in_sizes, int n_in,
                              void* d_out, int out_size, void* d_ws, size_t ws_size,
                              hipStream_t stream) {
    const float* emb = (const float*)d_in[0];
    const float* W1  = (const float*)d_in[1];
    const float* b1  = (const float*)d_in[2];
    const float* W2  = (const float*)d_in[3];
    const float* b2  = (const float*)d_in[4];
    const int*   ei  = (const int*)d_in[5];

    const int n  = in_sizes[0] / 64;   // 100000 nodes (< 2^17, fits pack)
    const int ne = in_sizes[5] / 2;    // 1600000 edges
    const int* src = ei;
    const int* dst = ei + ne;
    const int nb = (n + NB_MASK) >> NB_SHIFT;   // 782 buckets

    // ---- workspace layout (~39 MB) ----
    char* ws = (char*)d_ws;
    size_t off = 0;
    auto alloc = [&](size_t bytes) { void* p = ws + off; off = (off + bytes + 63) & ~size_t(63); return p; };
    int*      bcnt    = (int*)     alloc((size_t)nb * 4);
    int*      bbase   = (int*)     alloc((size_t)(nb + 1) * 4);
    int*      bcur    = (int*)     alloc((size_t)nb * 4);
    unsigned* tpack   = (unsigned*)alloc((size_t)ne * 4);
    int*      csrc    = (int*)     alloc((size_t)ne * 4);
    int*      offsets = (int*)     alloc((size_t)(n + 1) * 4);
    float*    dinv    = (float*)   alloc((size_t)n * 4);
    float*    Y       = (float*)   alloc((size_t)n * 64 * 4);
    (void)ws_size;

    float* out = (float*)d_out;   // doubles as X1 between the layers

    hipMemsetAsync(bcnt, 0, (size_t)nb * 4, stream);

    const int pb = (ne + EPB - 1) / EPB;   // partition blocks
    const int wb = (n + 3) / 4;            // 1 wave per node
    const int gb = min((n + 63) / 64, 2048);

    k_bhist<<<pb, 256, 0, stream>>>(dst, bcnt, ne, nb);
    k_bscan<<<1, 64, 0, stream>>>(bcnt, bbase, bcur, nb, offsets, n, ne);
    k_part <<<pb, 256, 0, stream>>>(src, dst, bcur, tpack, ne, nb);
    k_bin  <<<nb, 256, 0, stream>>>(tpack, bbase, csrc, offsets, dinv, n);

    // layer 1
    k_agg   <<<wb, 256, 0, stream>>>(emb, offsets, csrc, dinv, Y, n);
    k_gemm64<<<gb, 256, 0, stream>>>(Y, W1, b1, out, n);
    // layer 2
    k_agg   <<<wb, 256, 0, stream>>>(out, offsets, csrc, dinv, Y, n);
    k_gemm64<<<gb, 256, 0, stream>>>(Y, W2, b2, out, n);
}